// Round 8
// baseline (188.700 us; speedup 1.0000x reference)
//
#include <hip/hip_runtime.h>
#include <math.h>

// Problem constants (from reference)
constexpr int B_ = 16, T_ = 256, D_ = 384, M_ = 2048, F_ = 256, NMEL_ = 80;
constexpr float PACE_ = 1.0f, MAXDUR_ = 75.0f;
constexpr int R_ = B_ * T_;  // 4096 total rows

typedef unsigned short ushort_t;
typedef __attribute__((ext_vector_type(8))) short bf16x8;
typedef __attribute__((ext_vector_type(4))) float f32x4_;

static __device__ __forceinline__ ushort_t f2bf(float x) {
    union { float f; unsigned int u; } v; v.f = x;
    const unsigned int r = v.u + 0x7fffu + ((v.u >> 16) & 1u);  // RNE
    return (ushort_t)(r >> 16);
}
static __device__ __forceinline__ float bf2f(ushort_t h) {
    union { float f; unsigned int u; } v; v.u = ((unsigned int)h) << 16;
    return v.f;
}

// ---------------------------------------------------------------------------
// Weight repack device job: w[F_,CIN,3] fp32 -> bf16 16x16x32 B-frag order:
//   p[ ((k*(F_/16)+fn)*(CIN/32)+c)*512 + lane*8 + j ]
//     = w[f=fn*16+(lane&15)][d=c*32+(lane>>4)*8+j][k]   (validated r4-r7)
// ---------------------------------------------------------------------------
template <int CIN>
static __device__ void repack_job(int bx, const float* __restrict__ w,
                                  ushort_t* __restrict__ p)
{
    constexpr int NC = CIN / 32;
    const int gid = bx * 256 + threadIdx.x;   // over 3*F_*CIN/8
    const int lane = gid & 63;
    int rest = gid >> 6;
    const int c = rest % NC;  rest /= NC;
    const int fn = rest % (F_ / 16);
    const int k  = rest / (F_ / 16);
    const int f = fn * 16 + (lane & 15);
    const int d = c * 32 + (lane >> 4) * 8;
    uint4 o;
    ushort_t* op = (ushort_t*)&o;
#pragma unroll
    for (int j = 0; j < 8; j++)
        op[j] = f2bf(w[((size_t)f * CIN + d + j) * 3 + k]);
    ((uint4*)p)[gid] = o;
}

// ---------------------------------------------------------------------------
// prep mega-kernel: all input-only work in ONE dispatch (validated r5-r7).
// ---------------------------------------------------------------------------
constexpr int NA_ = 144, NB_ = 96, NCB_ = 15, ND_ = R_ * D_ / 4 / 256, NE_ = B_;
constexpr int OFF_B = 2 * NA_;            // 288
constexpr int OFF_C = OFF_B + 2 * NB_;    // 480
constexpr int OFF_D = OFF_C + NCB_;       // 495
constexpr int OFF_E = OFF_D + ND_;        // 2031
constexpr int NPREP = OFF_E + NE_;        // 2047

__global__ __launch_bounds__(256) void prep_kernel(
    const float* __restrict__ dc0w, const float* __restrict__ pc0w,
    const float* __restrict__ dc1w, const float* __restrict__ pc1w,
    const float* __restrict__ projw,
    const float* __restrict__ enc_out, const float* __restrict__ maskp,
    const float* __restrict__ pt,
    const float* __restrict__ we, const float* __restrict__ be,
    const int* __restrict__ dur,
    ushort_t* __restrict__ pw0d, ushort_t* __restrict__ pw0p,
    ushort_t* __restrict__ pw1d, ushort_t* __restrict__ pw1p,
    ushort_t* __restrict__ pwb, ushort_t* __restrict__ encb,
    ushort_t* __restrict__ xb,
    int* __restrict__ idx_out, float* __restrict__ dec_mask)
{
    __shared__ int cums[T_];
    const int bx = blockIdx.x;

    if (bx < OFF_B) {                                   // job A
        if (bx < NA_) repack_job<D_>(bx, dc0w, pw0d);
        else          repack_job<D_>(bx - NA_, pc0w, pw0p);
    } else if (bx < OFF_C) {                            // job B
        const int b2 = bx - OFF_B;
        if (b2 < NB_) repack_job<F_>(b2, dc1w, pw1d);
        else          repack_job<F_>(b2 - NB_, pc1w, pw1p);
    } else if (bx < OFF_D) {                            // job C: proj repack
        const int gid = (bx - OFF_C) * 256 + threadIdx.x;  // over 3840
        const int lane = gid & 63;
        const int rest = gid >> 6;
        const int nt = rest % 5;
        const int c  = rest / 5;
        const int n = nt * 16 + (lane & 15);
        const int k = c * 32 + (lane >> 4) * 8;
        uint4 o;
        ushort_t* op = (ushort_t*)&o;
#pragma unroll
        for (int j = 0; j < 8; j++)
            op[j] = f2bf(projw[(size_t)n * D_ + k + j]);
        ((uint4*)pwb)[gid] = o;
    } else if (bx < OFF_E) {                            // job D: pitch add + xb cast
        const int gid = (bx - OFF_D) * 256 + threadIdx.x;  // over R_*D_/4
        const int dq = gid % (D_ / 4);
        const int bt = gid / (D_ / 4);
        const int t = bt & 255, b = bt >> 8;
        const int d = dq * 4;
        const float4 e = ((const float4*)enc_out)[gid];
        const float m  = maskp[b * T_ + t];
        const float p0 = (t > 0)   ? pt[b * T_ + t - 1] : 0.f;
        const float p1 = pt[b * T_ + t];
        const float p2 = (t < 255) ? pt[b * T_ + t + 1] : 0.f;
        const float* ev = (const float*)&e;
        ushort4 o, ox;
        ushort_t* op = (ushort_t*)&o;
        ushort_t* oxp = (ushort_t*)&ox;
#pragma unroll
        for (int dd = 0; dd < 4; dd++) {
            float s = be[d + dd];
            s = fmaf(we[(d + dd) * 3 + 0], p0, s);
            s = fmaf(we[(d + dd) * 3 + 1], p1, s);
            s = fmaf(we[(d + dd) * 3 + 2], p2, s);
            op[dd]  = f2bf(ev[dd] + s);
            oxp[dd] = f2bf(ev[dd] * m);
        }
        ((ushort4*)encb)[gid] = o;
        ((ushort4*)xb)[gid]   = ox;
    } else {                                            // job E: regulate
        const int b = bx - OFF_E, t = threadIdx.x;
        cums[t] = (int)rintf((float)dur[b * T_ + t] / PACE_);
        __syncthreads();
        for (int off = 1; off < T_; off <<= 1) {
            int v = cums[t];
            if (t >= off) v += cums[t - off];
            __syncthreads();
            cums[t] = v;
            __syncthreads();
        }
        const int dec_len = min(cums[T_ - 1], M_);
#pragma unroll
        for (int r = 0; r < M_ / T_; r++) {
            const int j = r * T_ + t;
            int lo = 0, hi = T_;
            while (lo < hi) {
                const int mid = (lo + hi) >> 1;
                if (cums[mid] <= j) lo = mid + 1; else hi = mid;
            }
            idx_out[b * M_ + j]  = min(lo, T_ - 1);
            dec_mask[b * M_ + j] = (j < dec_len) ? 1.f : 0.f;
        }
    }
}

// ---------------------------------------------------------------------------
// conv0: Conv1d(K=3,SAME)+bias+ReLU as MFMA GEMM (validated r7 structure).
// Block: 64 rows x 128 f; grid (R_/64, 2, 2z). A+B double-buffered in LDS;
// epilogue through LDS -> coalesced 16B stores. Output = pre-LN h (bf16).
// ---------------------------------------------------------------------------
template <int CIN>
__global__ __launch_bounds__(256) void conv_kernel(
    const ushort_t* __restrict__ in0, const ushort_t* __restrict__ in1,
    const ushort_t* __restrict__ pw0, const ushort_t* __restrict__ pw1,
    const float* __restrict__ bias0, const float* __restrict__ bias1,
    ushort_t* __restrict__ out0, ushort_t* __restrict__ out1)
{
    constexpr int NC = CIN / 32;
    __shared__ __align__(16) char smem[70272];
    ushort_t* Asm = (ushort_t*)smem;             // [2][5280]
    ushort_t* Bsm = (ushort_t*)(smem + 21120);   // [2][12288]

    const int z = blockIdx.z;
    const ushort_t* x  = z ? in1 : in0;
    const ushort_t* pw = z ? pw1 : pw0;
    const float* bias  = z ? bias1 : bias0;
    ushort_t* out      = z ? out1 : out0;

    const int r0 = blockIdx.x * 64;
    const int bb = r0 >> 8;
    const int tl = r0 & 255;
    const int fb = blockIdx.y * 8;
    const int tid = threadIdx.x;

    uint4 areg0, areg1;
    uint4 breg[6];

    auto loadA = [&](int c) {
        {   const int row = tid >> 2, jc = (tid & 3) * 8;
            const int t = tl - 1 + row;
            areg0 = make_uint4(0u, 0u, 0u, 0u);
            if (t >= 0 && t < 256)
                areg0 = *(const uint4*)(x + (size_t)(bb * 256 + t) * CIN + c * 32 + jc);
        }
        if (tid < 8) {
            const int u = 256 + tid;
            const int row = u >> 2, jc = (u & 3) * 8;
            const int t = tl - 1 + row;
            areg1 = make_uint4(0u, 0u, 0u, 0u);
            if (t >= 0 && t < 256)
                areg1 = *(const uint4*)(x + (size_t)(bb * 256 + t) * CIN + c * 32 + jc);
        }
    };
    auto storeA = [&](int buf) {
        ushort_t* d = Asm + buf * 5280;
        *(uint4*)(d + (tid >> 2) * 40 + (tid & 3) * 8) = areg0;
        if (tid < 8) {
            const int u = 256 + tid;
            *(uint4*)(d + (u >> 2) * 40 + (u & 3) * 8) = areg1;
        }
    };
    auto loadB = [&](int c) {
#pragma unroll
        for (int jj = 0; jj < 6; jj++) {
            const int u = jj * 256 + tid;
            const int frag = u >> 6, within = u & 63;
            const int tap = frag >> 3, fnl = frag & 7;
            breg[jj] = *(const uint4*)(
                pw + (((size_t)(tap * 16 + fb + fnl) * NC + c) << 9) + within * 8);
        }
    };
    auto storeB = [&](int buf) {
        ushort_t* d = Bsm + buf * 12288;
#pragma unroll
        for (int jj = 0; jj < 6; jj++) {
            const int u = jj * 256 + tid;
            *(uint4*)(d + u * 8) = breg[jj];
        }
    };

    loadA(0); loadB(0); storeA(0); storeB(0);
    __syncthreads();

    const int w = tid >> 6, l = tid & 63;
    const int wy = w >> 1, wx = w & 1;
    const int q = l >> 4, lm = l & 15;

    f32x4_ acc[2][4];
#pragma unroll
    for (int mi = 0; mi < 2; mi++)
#pragma unroll
        for (int nf = 0; nf < 4; nf++)
#pragma unroll
            for (int i = 0; i < 4; i++) acc[mi][nf][i] = 0.f;

    for (int c = 0; c < NC; c++) {
        const int buf = c & 1;
        if (c + 1 < NC) { loadA(c + 1); loadB(c + 1); }

        const ushort_t* Ab = Asm + buf * 5280;
        const ushort_t* Bb = Bsm + buf * 12288;
        bf16x8 a[2][3], b[4][3];
#pragma unroll
        for (int mi = 0; mi < 2; mi++)
#pragma unroll
            for (int tap = 0; tap < 3; tap++)
                a[mi][tap] = *(const bf16x8*)(
                    Ab + ((wy * 2 + mi) * 16 + lm + tap) * 40 + q * 8);
#pragma unroll
        for (int nf = 0; nf < 4; nf++)
#pragma unroll
            for (int tap = 0; tap < 3; tap++)
                b[nf][tap] = *(const bf16x8*)(
                    Bb + (tap * 8 + wx * 4 + nf) * 512 + l * 8);
#pragma unroll
        for (int tap = 0; tap < 3; tap++)
#pragma unroll
            for (int nf = 0; nf < 4; nf++)
#pragma unroll
                for (int mi = 0; mi < 2; mi++)
                    acc[mi][nf] = __builtin_amdgcn_mfma_f32_16x16x32_bf16(
                        a[mi][tap], b[nf][tap], acc[mi][nf], 0, 0, 0);

        if (c + 1 < NC) { storeA((c + 1) & 1); storeB((c + 1) & 1); }
        __syncthreads();
    }

    ushort_t* hs = (ushort_t*)smem;
    const int fbase = fb * 16;
#pragma unroll
    for (int nf = 0; nf < 4; nf++) {
        const int fl = (wx * 4 + nf) * 16 + lm;
        const float bs = bias[fbase + fl];
#pragma unroll
        for (int mi = 0; mi < 2; mi++)
#pragma unroll
            for (int r = 0; r < 4; r++) {
                const int row = (wy * 2 + mi) * 16 + q * 4 + r;
                hs[row * 136 + fl] = f2bf(fmaxf(acc[mi][nf][r] + bs, 0.f));
            }
    }
    __syncthreads();
#pragma unroll
    for (int p = 0; p < 4; p++) {
        const int u = p * 256 + tid;
        const int row = u >> 4, fo = (u & 15) * 8;
        *(uint4*)(out + (size_t)(r0 + row) * F_ + fbase + fo) =
            *(const uint4*)(hs + row * 136 + fo);
    }
}

// ---------------------------------------------------------------------------
// predtail: fused LN0 + conv1 + LN1 + FC head.  Grid (R_/32, 2z).
// Block = 32 output rows x full F=256. Steps:
//  1) load h0 rows tl-1..tl+32 (34, zero outside batch), LN0 -> LDS bf16
//  2) conv1 MFMA: A from LDS, B-frags per-lane from L2 (r4-validated index)
//  3) bias+ReLU -> LDS h1
//  4) LN1 + FC dot per row -> predictions (only [B,T] writes)
// ---------------------------------------------------------------------------
constexpr int HS0W = F_ + 8;   // 264 ushort row stride
__global__ __launch_bounds__(256) void predtail_kernel(
    const ushort_t* __restrict__ h0d, const ushort_t* __restrict__ h0p,
    const float* __restrict__ n0g_d, const float* __restrict__ n0b_d,
    const float* __restrict__ n0g_p, const float* __restrict__ n0b_p,
    const ushort_t* __restrict__ pw1d, const ushort_t* __restrict__ pw1p,
    const float* __restrict__ c1b_d, const float* __restrict__ c1b_p,
    const float* __restrict__ n1g_d, const float* __restrict__ n1b_d,
    const float* __restrict__ n1g_p, const float* __restrict__ n1b_p,
    const float* __restrict__ fcw_d, const float* __restrict__ fcw_p,
    const float* __restrict__ fcb_d, const float* __restrict__ fcb_p,
    const float* __restrict__ mask,
    float* __restrict__ log_dur, float* __restrict__ pitch_pred,
    float* __restrict__ dur_pred)
{
    __shared__ ushort_t hs0[34 * HS0W];   // 17.9 KB  LN0 output (bf16)
    __shared__ ushort_t hs1[32 * HS0W];   // 16.9 KB  conv1 output (bf16)

    const int z = blockIdx.y;
    const ushort_t* h0 = z ? h0p : h0d;
    const float* n0g = z ? n0g_p : n0g_d;
    const float* n0b = z ? n0b_p : n0b_d;
    const ushort_t* pw1 = z ? pw1p : pw1d;
    const float* c1b = z ? c1b_p : c1b_d;
    const float* n1g = z ? n1g_p : n1g_d;
    const float* n1b = z ? n1b_p : n1b_d;
    const float* fcw = z ? fcw_p : fcw_d;
    const float* fcb = z ? fcb_p : fcb_d;
    float* pred = z ? pitch_pred : log_dur;

    const int r0 = blockIdx.x * 32;
    const int bb = r0 >> 8;
    const int tl = r0 & 255;
    const int tid = threadIdx.x;
    const int lh = tid & 31;          // 32 lanes per row

    // ---- 1) LN0 of rows tl-1 .. tl+32 -> hs0 (zero outside batch) ----
    {
        const float4 gv0 = ((const float4*)n0g)[lh * 2];
        const float4 gv1 = ((const float4*)n0g)[lh * 2 + 1];
        const float4 bv0 = ((const float4*)n0b)[lh * 2];
        const float4 bv1 = ((const float4*)n0b)[lh * 2 + 1];
        const float gg[8]  = {gv0.x, gv0.y, gv0.z, gv0.w, gv1.x, gv1.y, gv1.z, gv1.w};
        const float bbv[8] = {bv0.x, bv0.y, bv0.z, bv0.w, bv1.x, bv1.y, bv1.z, bv1.w};
        for (int rr = tid >> 5; rr < 34; rr += 8) {
            const int t = tl - 1 + rr;
            uint4 ov = make_uint4(0u, 0u, 0u, 0u);
            if (t >= 0 && t < 256) {
                const uint4 hv4 = *(const uint4*)(h0 + (size_t)(bb * 256 + t) * F_ + lh * 8);
                const ushort_t* hp = (const ushort_t*)&hv4;
                float v[8], sm = 0.f, sq = 0.f;
#pragma unroll
                for (int j = 0; j < 8; j++) {
                    v[j] = bf2f(hp[j]); sm += v[j]; sq += v[j] * v[j];
                }
#pragma unroll
                for (int off = 16; off >= 1; off >>= 1) {
                    sm += __shfl_xor(sm, off, 32);
                    sq += __shfl_xor(sq, off, 32);
                }
                const float mu = sm * (1.f / F_);
                const float rs = rsqrtf(sq * (1.f / F_) - mu * mu + 1e-5f);
                ushort_t* op = (ushort_t*)&ov;
#pragma unroll
                for (int j = 0; j < 8; j++)
                    op[j] = f2bf((v[j] - mu) * rs * gg[j] + bbv[j]);
            }
            *(uint4*)(hs0 + rr * HS0W + lh * 8) = ov;
        }
    }
    __syncthreads();

    // ---- 2) conv1 MFMA (K=256, 8 chunks); wave w -> fn = w*4..w*4+3 ----
    const int w = tid >> 6, l = tid & 63;
    const int q = l >> 4, lm = l & 15;

    f32x4_ acc[2][4];
#pragma unroll
    for (int mi = 0; mi < 2; mi++)
#pragma unroll
        for (int nf = 0; nf < 4; nf++)
#pragma unroll
            for (int i = 0; i < 4; i++) acc[mi][nf][i] = 0.f;

    for (int c = 0; c < F_ / 32; c++) {
        bf16x8 a[2][3];
#pragma unroll
        for (int mi = 0; mi < 2; mi++)
#pragma unroll
            for (int tap = 0; tap < 3; tap++)
                a[mi][tap] = *(const bf16x8*)(
                    hs0 + (mi * 16 + lm + tap) * HS0W + c * 32 + q * 8);
#pragma unroll
        for (int tap = 0; tap < 3; tap++)
#pragma unroll
            for (int nf = 0; nf < 4; nf++) {
                const bf16x8 b = *(const bf16x8*)(
                    pw1 + (((size_t)(tap * 16 + w * 4 + nf) * (F_ / 32) + c) << 9) + l * 8);
#pragma unroll
                for (int mi = 0; mi < 2; mi++)
                    acc[mi][nf] = __builtin_amdgcn_mfma_f32_16x16x32_bf16(
                        a[mi][tap], b, acc[mi][nf], 0, 0, 0);
            }
    }
    __syncthreads();

    // ---- 3) bias + ReLU -> hs1 ----
#pragma unroll
    for (int nf = 0; nf < 4; nf++) {
        const int f = (w * 4 + nf) * 16 + lm;
        const float bs = c1b[f];
#pragma unroll
        for (int mi = 0; mi < 2; mi++)
#pragma unroll
            for (int r = 0; r < 4; r++) {
                const int row = mi * 16 + q * 4 + r;
                hs1[row * HS0W + f] = f2bf(fmaxf(acc[mi][nf][r] + bs, 0.f));
            }
    }
    __syncthreads();

    // ---- 4) LN1 + FC per output row ----
    {
        const float4 gv0 = ((const float4*)n1g)[lh * 2];
        const float4 gv1 = ((const float4*)n1g)[lh * 2 + 1];
        const float4 bv0 = ((const float4*)n1b)[lh * 2];
        const float4 bv1 = ((const float4*)n1b)[lh * 2 + 1];
        const float4 wv0 = ((const float4*)fcw)[lh * 2];
        const float4 wv1 = ((const float4*)fcw)[lh * 2 + 1];
        const float gg[8]  = {gv0.x, gv0.y, gv0.z, gv0.w, gv1.x, gv1.y, gv1.z, gv1.w};
        const float bbv[8] = {bv0.x, bv0.y, bv0.z, bv0.w, bv1.x, bv1.y, bv1.z, bv1.w};
        const float ww[8]  = {wv0.x, wv0.y, wv0.z, wv0.w, wv1.x, wv1.y, wv1.z, wv1.w};
        const float fcbv = fcb[0];
        for (int rr = tid >> 5; rr < 32; rr += 8) {
            const uint4 hv4 = *(const uint4*)(hs1 + rr * HS0W + lh * 8);
            const ushort_t* hp = (const ushort_t*)&hv4;
            float v[8], sm = 0.f, sq = 0.f;
#pragma unroll
            for (int j = 0; j < 8; j++) {
                v[j] = bf2f(hp[j]); sm += v[j]; sq += v[j] * v[j];
            }
#pragma unroll
            for (int off = 16; off >= 1; off >>= 1) {
                sm += __shfl_xor(sm, off, 32);
                sq += __shfl_xor(sq, off, 32);
            }
            const float mu = sm * (1.f / F_);
            const float rs = rsqrtf(sq * (1.f / F_) - mu * mu + 1e-5f);
            float p = 0.f;
#pragma unroll
            for (int j = 0; j < 8; j++)
                p += ((v[j] - mu) * rs * gg[j] + bbv[j]) * ww[j];
#pragma unroll
            for (int off = 16; off >= 1; off >>= 1) p += __shfl_xor(p, off, 32);
            if (lh == 0) {
                const int row = r0 + rr;
                const float pp = (p + fcbv) * mask[row];
                pred[row] = pp;
                if (!z) dur_pred[row] = fminf(fmaxf(expf(pp) - 1.f, 0.f), MAXDUR_);
            }
        }
    }
}

// ---------------------------------------------------------------------------
// mel gather-GEMM via MFMA 16x16x32 (validated r5-r7).
// ---------------------------------------------------------------------------
__global__ __launch_bounds__(256, 2) void mel_mfma_kernel(
    const ushort_t* __restrict__ encb, const int* __restrict__ idx,
    const float* __restrict__ dmask, const ushort_t* __restrict__ pwb,
    const float* __restrict__ pb, float* __restrict__ mel)
{
    __shared__ ushort_t Bs[5 * 12 * 512];
    __shared__ int ids[64];
    const int b  = blockIdx.y;
    const int j0 = blockIdx.x * 64;
    const int tid = threadIdx.x;

#pragma unroll
    for (int jj = 0; jj < 15; jj++)
        ((uint4*)Bs)[jj * 256 + tid] = ((const uint4*)pwb)[jj * 256 + tid];
    if (tid < 64) ids[tid] = idx[b * M_ + j0 + tid];
    __syncthreads();

    const int w = tid >> 6, l = tid & 63;
    const int q = l >> 4, lm = l & 15;
    const int row = ids[w * 16 + lm];
    const ushort_t* ap = encb + ((size_t)(b * 256 + row)) * D_ + q * 8;

    bf16x8 a[D_ / 32];
#pragma unroll
    for (int c = 0; c < D_ / 32; c++)
        a[c] = *(const bf16x8*)(ap + c * 32);

    f32x4_ acc[5];
#pragma unroll
    for (int nt = 0; nt < 5; nt++)
#pragma unroll
        for (int i = 0; i < 4; i++) acc[nt][i] = 0.f;

#pragma unroll
    for (int c = 0; c < D_ / 32; c++) {
#pragma unroll
        for (int nt = 0; nt < 5; nt++) {
            const bf16x8 bv = *(const bf16x8*)(&Bs[(c * 5 + nt) * 512 + l * 8]);
            acc[nt] = __builtin_amdgcn_mfma_f32_16x16x32_bf16(a[c], bv, acc[nt], 0, 0, 0);
        }
    }

    float msk[4];
#pragma unroll
    for (int r = 0; r < 4; r++)
        msk[r] = dmask[b * M_ + j0 + w * 16 + q * 4 + r];
#pragma unroll
    for (int nt = 0; nt < 5; nt++) {
        const int n = nt * 16 + lm;
        const float bb = pb[n];
#pragma unroll
        for (int r = 0; r < 4; r++) {
            const int j = j0 + w * 16 + q * 4 + r;
            mel[((size_t)b * M_ + j) * NMEL_ + n] = msk[r] * acc[nt][r] + bb;
        }
    }
}

// ---------------------------------------------------------------------------
extern "C" void kernel_launch(void* const* d_in, const int* in_sizes, int n_in,
                              void* d_out, int out_size, void* d_ws, size_t ws_size,
                              hipStream_t stream)
{
    const float* enc_out   = (const float*)d_in[0];
    const float* enc_mask  = (const float*)d_in[1];
    const float* pitch_tgt = (const float*)d_in[2];
    const int*   durations = (const int*)d_in[3];

    const float* dur_c0_w = (const float*)d_in[4];
    const float* dur_c0_b = (const float*)d_in[5];
    const float* dur_n0_g = (const float*)d_in[6];
    const float* dur_n0_b = (const float*)d_in[7];
    const float* dur_c1_w = (const float*)d_in[8];
    const float* dur_c1_b = (const float*)d_in[9];
    const float* dur_n1_g = (const float*)d_in[10];
    const float* dur_n1_b = (const float*)d_in[11];
    const float* dur_fc_w = (const float*)d_in[12];
    const float* dur_fc_b = (const float*)d_in[13];

    const float* pit_c0_w = (const float*)d_in[14];
    const float* pit_c0_b = (const float*)d_in[15];
    const float* pit_n0_g = (const float*)d_in[16];
    const float* pit_n0_b = (const float*)d_in[17];
    const float* pit_c1_w = (const float*)d_in[18];
    const float* pit_c1_b = (const float*)d_in[19];
    const float* pit_n1_g = (const float*)d_in[20];
    const float* pit_n1_b = (const float*)d_in[21];
    const float* pit_fc_w = (const float*)d_in[22];
    const float* pit_fc_b = (const float*)d_in[23];

    const float* pemb_w = (const float*)d_in[24];
    const float* pemb_b = (const float*)d_in[25];
    const float* proj_w = (const float*)d_in[26];
    const float* proj_b = (const float*)d_in[27];

    // Output slices (flat, in return order), all fp32.
    float* out       = (float*)d_out;
    float* mel_out   = out;                                   // [B,M,NMEL]
    float* dec_mask  = mel_out + (size_t)B_ * M_ * NMEL_;     // [B,M,1]
    float* dur_pred  = dec_mask + (size_t)B_ * M_;            // [B,T]
    float* log_dur   = dur_pred + (size_t)B_ * T_;            // [B,T]
    float* pitch_prd = log_dur + (size_t)B_ * T_;             // [B,T]

    // Workspace layout (~13 MiB)
    char* wp = (char*)d_ws;
    ushort_t* pw0d = (ushort_t*)wp; wp += (size_t)3 * F_ * D_ * 2;   // 590 KB
    ushort_t* pw0p = (ushort_t*)wp; wp += (size_t)3 * F_ * D_ * 2;
    ushort_t* pw1d = (ushort_t*)wp; wp += (size_t)3 * F_ * F_ * 2;   // 393 KB
    ushort_t* pw1p = (ushort_t*)wp; wp += (size_t)3 * F_ * F_ * 2;
    ushort_t* pwb  = (ushort_t*)wp; wp += (size_t)5 * 12 * 512 * 2;  // 61 KB
    ushort_t* encb = (ushort_t*)wp; wp += (size_t)R_ * D_ * 2;       // 3.15 MB
    ushort_t* xb   = (ushort_t*)wp; wp += (size_t)R_ * D_ * 2;       // 3.15 MB
    ushort_t* h_d  = (ushort_t*)wp; wp += (size_t)R_ * F_ * 2;       // 2.10 MB
    ushort_t* h_p  = (ushort_t*)wp; wp += (size_t)R_ * F_ * 2;
    int*      idx  = (int*)wp;                                       // 131 KB

    const dim3 blk(256);

    // 1) all input-only prep (weight repacks, encb, xb cast, regulate)
    prep_kernel<<<NPREP, blk, 0, stream>>>(
        dur_c0_w, pit_c0_w, dur_c1_w, pit_c1_w, proj_w,
        enc_out, enc_mask, pitch_tgt, pemb_w, pemb_b, durations,
        pw0d, pw0p, pw1d, pw1p, pwb, encb, xb, idx, dec_mask);

    // 2) conv0 (dur & pitch) -> h (pre-LN, bf16)
    conv_kernel<D_><<<dim3(R_ / 64, 2, 2), blk, 0, stream>>>(
        xb, xb, pw0d, pw0p, dur_c0_b, pit_c0_b, h_d, h_p);

    // 3) fused LN0 + conv1 + LN1 + FC -> predictions only
    predtail_kernel<<<dim3(R_ / 32, 2), blk, 0, stream>>>(
        h_d, h_p, dur_n0_g, dur_n0_b, pit_n0_g, pit_n0_b,
        pw1d, pw1p, dur_c1_b, pit_c1_b,
        dur_n1_g, dur_n1_b, pit_n1_g, pit_n1_b,
        dur_fc_w, pit_fc_w, dur_fc_b, pit_fc_b, enc_mask,
        log_dur, pitch_prd, dur_pred);

    // 4) gather + projection to mel
    mel_mfma_kernel<<<dim3(M_ / 64, B_), blk, 0, stream>>>(
        encb, idx, dec_mask, pwb, proj_b, mel_out);
}